// Round 1
// baseline (1272.923 us; speedup 1.0000x reference)
//
#include <hip/hip_runtime.h>

typedef __bf16 bf16x8 __attribute__((ext_vector_type(8)));
typedef float f32x4 __attribute__((ext_vector_type(4)));

static __device__ __forceinline__ unsigned short f2bf(float f) {
    union { float f; unsigned int u; } v; v.f = f;
    unsigned int r = v.u + 0x7fffu + ((v.u >> 16) & 1u);
    return (unsigned short)(r >> 16);
}

// ---------------- deg[r][n] = count of edges (et=r, dst=n) ----------------
__global__ void deg_kernel(const int* __restrict__ dst, const int* __restrict__ et,
                           float* __restrict__ deg, int E, int N) {
    int i = blockIdx.x * blockDim.x + threadIdx.x;
    int stride = gridDim.x * blockDim.x;
    for (; i < E; i += stride)
        atomicAdd(&deg[(size_t)et[i] * N + dst[i]], 1.0f);
}

// ------------- Wt[r][o][d] (bf16): r<R -> W_r[r][d][o]; r==R -> W0_w[o][d] -------------
__global__ void wt_kernel(const float* __restrict__ Wr, const float* __restrict__ W0w,
                          unsigned short* __restrict__ Wt, int R) {
    int id = blockIdx.x * blockDim.x + threadIdx.x;
    int total = (R + 1) * 65536;
    if (id >= total) return;
    int r = id >> 16, o = (id >> 8) & 255, d = id & 255;
    float v = (r < R) ? Wr[(((size_t)r << 8) + d) * 256 + o]
                      : W0w[((size_t)o << 8) + d];
    Wt[id] = f2bf(v);
}

// ------------- s[(et-r0)][dst][:] += x[src][:] / deg[et][dst], et in [r0,r1) -------------
// one wave per edge (grid-stride); lane covers 4 dims via float4
__global__ void scatter_kernel(const float* __restrict__ x, const int* __restrict__ src,
                               const int* __restrict__ dst, const int* __restrict__ et,
                               const float* __restrict__ deg, float* __restrict__ s,
                               int E, int N, int r0, int r1) {
    const int lane = threadIdx.x & 63;
    int wave = blockIdx.x * (blockDim.x >> 6) + (threadIdx.x >> 6);
    const int nwave = gridDim.x * (blockDim.x >> 6);
    for (int e = wave; e < E; e += nwave) {
        int t = et[e];
        if (t < r0 || t >= r1) continue;           // wave-uniform branch
        int sn = src[e], dn = dst[e];
        float scale = 1.0f / deg[(size_t)t * N + dn];
        float4 xv = *reinterpret_cast<const float4*>(&x[((size_t)sn << 8) + (lane << 2)]);
        float* sp = s + ((((size_t)(t - r0)) * N + dn) << 8) + (lane << 2);
        atomicAdd(sp + 0, xv.x * scale);
        atomicAdd(sp + 1, xv.y * scale);
        atomicAdd(sp + 2, xv.z * scale);
        atomicAdd(sp + 3, xv.w * scale);
    }
}

// ------------- grouped GEMM: out[M,256] (+)= sum_sl A_sl[M,256] * Wt[rg][:,:]^T -------------
// A slices: nrel slices of S (f32, converted to bf16 on stage) + optional self-loop slice X.
// BM=32 rows, BN=128 cols, 128 threads (2 waves, 16 rows each, 8 n-frags).
#define GBM 32
#define GBN 128
__global__ __launch_bounds__(128) void gemm_kernel(
    const float* __restrict__ S, const float* __restrict__ X,
    const unsigned short* __restrict__ Wt, const float* __restrict__ bias,
    float* __restrict__ out, int M, int nrel, int r0, int selfIdx, int withSelf, int first)
{
    __shared__ __align__(16) unsigned short lds_a[GBM * 40];  // 32 rows x 32k, pad->40
    __shared__ __align__(16) unsigned short lds_b[GBN * 40];  // 128 n  x 32k, pad->40
    const int tid = threadIdx.x;
    const int lane = tid & 63, w = tid >> 6;
    const int m0 = blockIdx.x * GBM, n0 = blockIdx.y * GBN;

    f32x4 acc[8] = {};
    const int nsl = nrel + (withSelf ? 1 : 0);
    for (int sl = 0; sl < nsl; ++sl) {
        const float* A = (sl < nrel) ? (S + (((size_t)sl * M) << 8)) : X;
        const unsigned short* Wb = Wt + ((size_t)((sl < nrel) ? (r0 + sl) : selfIdx) << 16);
        for (int k0 = 0; k0 < 256; k0 += 32) {
            // stage A: 32x32 f32 -> bf16 LDS (256 float4, 2/thread)
            #pragma unroll
            for (int i = 0; i < 2; ++i) {
                int idx = tid + (i << 7);
                int row = idx >> 3, cv = idx & 7;
                int gr = m0 + row;
                float4 v = make_float4(0.f, 0.f, 0.f, 0.f);
                if (gr < M) v = *reinterpret_cast<const float4*>(&A[((size_t)gr << 8) + k0 + (cv << 2)]);
                ushort4 h;
                h.x = f2bf(v.x); h.y = f2bf(v.y); h.z = f2bf(v.z); h.w = f2bf(v.w);
                *reinterpret_cast<ushort4*>(&lds_a[row * 40 + (cv << 2)]) = h;
            }
            // stage B: 128(n) x 32(k) bf16 from Wt (already [o][d] layout; 1024 ushort4, 8/thread)
            #pragma unroll
            for (int i = 0; i < 8; ++i) {
                int idx = tid + (i << 7);
                int n = idx >> 3, kv = idx & 7;
                ushort4 h = *reinterpret_cast<const ushort4*>(&Wb[(((size_t)(n0 + n)) << 8) + k0 + (kv << 2)]);
                *reinterpret_cast<ushort4*>(&lds_b[n * 40 + (kv << 2)]) = h;
            }
            __syncthreads();
            bf16x8 a = *reinterpret_cast<const bf16x8*>(&lds_a[(w * 16 + (lane & 15)) * 40 + ((lane >> 4) << 3)]);
            #pragma unroll
            for (int ni = 0; ni < 8; ++ni) {
                bf16x8 b = *reinterpret_cast<const bf16x8*>(&lds_b[(ni * 16 + (lane & 15)) * 40 + ((lane >> 4) << 3)]);
                acc[ni] = __builtin_amdgcn_mfma_f32_16x16x32_bf16(a, b, acc[ni], 0, 0, 0);
            }
            __syncthreads();
        }
    }
    // epilogue: C/D layout col=lane&15, row=(lane>>4)*4+reg
    const int rb = m0 + w * 16 + ((lane >> 4) << 2);
    const int cb = n0 + (lane & 15);
    #pragma unroll
    for (int ni = 0; ni < 8; ++ni) {
        int c = cb + ni * 16;
        #pragma unroll
        for (int j = 0; j < 4; ++j) {
            int r = rb + j;
            if (r < M) {
                float v = acc[ni][j];
                if (first) out[((size_t)r << 8) + c] = v + bias[c];
                else       out[((size_t)r << 8) + c] += v;
            }
        }
    }
}

extern "C" void kernel_launch(void* const* d_in, const int* in_sizes, int n_in,
                              void* d_out, int out_size, void* d_ws, size_t ws_size,
                              hipStream_t stream) {
    const float* x   = (const float*)d_in[0];
    const float* Wr  = (const float*)d_in[1];
    const float* W0w = (const float*)d_in[2];
    const float* W0b = (const float*)d_in[3];
    const int*   eidx= (const int*)d_in[4];
    const int*   et  = (const int*)d_in[5];
    const int N = in_sizes[0] / 256;      // 10000 nodes
    const int R = in_sizes[1] / 65536;    // 16 relations
    const int E = in_sizes[5];            // 320000 edges
    const int* src = eidx;
    const int* dst = eidx + E;
    float* out = (float*)d_out;

    // workspace layout: deg [R*N f32] | Wt [(R+1)*65536 bf16] | s [RC*N*256 f32]
    char* ws = (char*)d_ws;
    size_t off = 0;
    float* deg = (float*)(ws + off);
    off += (size_t)R * N * sizeof(float);
    off = (off + 255) & ~(size_t)255;
    unsigned short* Wt = (unsigned short*)(ws + off);
    off += (size_t)(R + 1) * 65536 * sizeof(unsigned short);
    off = (off + 255) & ~(size_t)255;
    const size_t per_rel = (size_t)N * 256 * sizeof(float);
    size_t avail = (ws_size > off) ? (ws_size - off) : 0;
    int RC = (int)(avail / per_rel);
    if (RC > R) RC = R;
    if (RC < 1) RC = 1;   // assumes ws_size >= ~13 MB
    float* sbuf = (float*)(ws + off);

    hipMemsetAsync(deg, 0, (size_t)R * N * sizeof(float), stream);
    deg_kernel<<<1024, 256, 0, stream>>>(dst, et, deg, E, N);
    {
        int total = (R + 1) * 65536;
        wt_kernel<<<(total + 255) / 256, 256, 0, stream>>>(Wr, W0w, Wt, R);
    }
    for (int r0 = 0, first = 1; r0 < R; r0 += RC, first = 0) {
        int rc = (R - r0 < RC) ? (R - r0) : RC;
        hipMemsetAsync(sbuf, 0, (size_t)rc * per_rel, stream);
        scatter_kernel<<<2048, 256, 0, stream>>>(x, src, dst, et, deg, sbuf, E, N, r0, r0 + rc);
        dim3 grid((N + GBM - 1) / GBM, 256 / GBN);
        gemm_kernel<<<grid, 128, 0, stream>>>(sbuf, x, Wt, W0b, out, N, rc, r0, R, first, first);
    }
}

// Round 2
// 256.014 us; speedup vs baseline: 4.9721x; 4.9721x over previous
//
#include <hip/hip_runtime.h>

typedef __bf16 bf16x8 __attribute__((ext_vector_type(8)));
typedef float f32x4 __attribute__((ext_vector_type(4)));

static __device__ __forceinline__ unsigned short f2bf(float f) {
    union { float f; unsigned int u; } v; v.f = f;
    unsigned int r = v.u + 0x7fffu + ((v.u >> 16) & 1u);
    return (unsigned short)(r >> 16);
}

// ---- histogram: deg[et*N+dst]++ (int atomics into 640KB, L2-resident) ----
__global__ void hist_kernel(const int* __restrict__ dst, const int* __restrict__ et,
                            int* __restrict__ deg, int E, int N) {
    int i = blockIdx.x * blockDim.x + threadIdx.x;
    if (i < E) atomicAdd(&deg[et[i] * N + dst[i]], 1);
}

// ---- 2-level exclusive scan over B bins (chunk=256) ----
__global__ void scan1_kernel(const int* __restrict__ deg, int* __restrict__ local,
                             int* __restrict__ bsum, int B) {
    __shared__ int tmp[256];
    int t = threadIdx.x, g = blockIdx.x * 256 + t;
    int v = (g < B) ? deg[g] : 0;
    tmp[t] = v; __syncthreads();
    for (int o = 1; o < 256; o <<= 1) {
        int u = (t >= o) ? tmp[t - o] : 0;
        __syncthreads();
        tmp[t] += u;
        __syncthreads();
    }
    if (g < B) local[g] = tmp[t] - v;          // exclusive within chunk
    if (t == 255) bsum[blockIdx.x] = tmp[t];   // chunk total
}

__global__ void scan2_kernel(const int* __restrict__ bsum, int* __restrict__ base, int nc) {
    __shared__ int tmp[1024];
    int t = threadIdx.x;
    int v = (t < nc) ? bsum[t] : 0;
    tmp[t] = v; __syncthreads();
    for (int o = 1; o < 1024; o <<= 1) {
        int u = (t >= o) ? tmp[t - o] : 0;
        __syncthreads();
        tmp[t] += u;
        __syncthreads();
    }
    if (t < nc) base[t] = tmp[t] - v;          // exclusive chunk base
}

__global__ void cursor_kernel(const int* __restrict__ local, const int* __restrict__ base,
                              int* __restrict__ cursor, int B) {
    int g = blockIdx.x * blockDim.x + threadIdx.x;
    if (g < B) cursor[g] = local[g] + base[g >> 8];
}

// ---- bucket the edges: srcs[] holds src ids grouped by (et,dst) bin ----
__global__ void scatter_ids_kernel(const int* __restrict__ src, const int* __restrict__ dst,
                                   const int* __restrict__ et, int* __restrict__ cursor,
                                   int* __restrict__ srcs, int E, int N) {
    int i = blockIdx.x * blockDim.x + threadIdx.x;
    if (i < E) {
        int b = et[i] * N + dst[i];
        int p = atomicAdd(&cursor[b], 1);
        srcs[p] = src[i];
    }
}

// ---- Wt[r][o][d] (bf16): r<R -> W_r[r][d][o]; r==R -> W0_w[o][d] ----
__global__ void wt_kernel(const float* __restrict__ Wr, const float* __restrict__ W0w,
                          unsigned short* __restrict__ Wt, int R) {
    int id = blockIdx.x * blockDim.x + threadIdx.x;
    int total = (R + 1) * 65536;
    if (id >= total) return;
    int r = id >> 16, o = (id >> 8) & 255, d = id & 255;
    float v = (r < R) ? Wr[(((size_t)r << 8) + d) * 256 + o]
                      : W0w[((size_t)o << 8) + d];
    Wt[id] = f2bf(v);
}

// ---- segment reduce: one wave per (r,dst) bin; s[bin][:] = (sum x[src]) / cnt, bf16 ----
__global__ void reduce_kernel(const float* __restrict__ x, const int* __restrict__ srcs,
                              const int* __restrict__ deg, const int* __restrict__ local,
                              const int* __restrict__ base, unsigned short* __restrict__ s,
                              int B) {
    int wid = blockIdx.x * (blockDim.x >> 6) + (threadIdx.x >> 6);
    if (wid >= B) return;
    const int lane = threadIdx.x & 63;
    int cnt = deg[wid];
    float a0 = 0.f, a1 = 0.f, a2 = 0.f, a3 = 0.f;
    if (cnt > 0) {
        int st = local[wid] + base[wid >> 8];
        for (int i = 0; i < cnt; ++i) {
            int sn = srcs[st + i];
            float4 xv = *reinterpret_cast<const float4*>(&x[((size_t)sn << 8) + (lane << 2)]);
            a0 += xv.x; a1 += xv.y; a2 += xv.z; a3 += xv.w;
        }
        float sc = 1.0f / (float)cnt;
        a0 *= sc; a1 *= sc; a2 *= sc; a3 *= sc;
    }
    ushort4 h;
    h.x = f2bf(a0); h.y = f2bf(a1); h.z = f2bf(a2); h.w = f2bf(a3);
    *reinterpret_cast<ushort4*>(&s[((size_t)wid << 8) + (lane << 2)]) = h;
}

// ---- grouped GEMM: out[M,256] = sum_sl A_sl[M,256] * Wt[sl]^T + bias ----
// A slices: R slices of s (bf16) + self-loop slice X (f32 -> bf16 on stage).
// BM=64 rows, BN=128 cols, 256 threads (4 waves, 16 rows each, 8 n-frags).
#define GBM 64
#define GBN 128
__global__ __launch_bounds__(256) void gemm_kernel(
    const unsigned short* __restrict__ S, const float* __restrict__ X,
    const unsigned short* __restrict__ Wt, const float* __restrict__ bias,
    float* __restrict__ out, int M, int R)
{
    __shared__ __align__(16) unsigned short lds_a[GBM * 40];
    __shared__ __align__(16) unsigned short lds_b[GBN * 40];
    const int tid = threadIdx.x;
    const int lane = tid & 63, w = tid >> 6;
    const int m0 = blockIdx.x * GBM, n0 = blockIdx.y * GBN;

    f32x4 acc[8] = {};
    for (int sl = 0; sl <= R; ++sl) {
        const unsigned short* Wb = Wt + ((size_t)sl << 16);
        const unsigned short* A = S + (((size_t)sl * M) << 8);
        for (int k0 = 0; k0 < 256; k0 += 32) {
            if (sl < R) {
                // stage A: 64x32 bf16 (512 ushort4, 2/thread)
                #pragma unroll
                for (int i = 0; i < 2; ++i) {
                    int idx = tid + (i << 8);
                    int row = idx >> 3, kv = idx & 7;
                    int gr = m0 + row;
                    ushort4 h = make_ushort4(0, 0, 0, 0);
                    if (gr < M) h = *reinterpret_cast<const ushort4*>(&A[((size_t)gr << 8) + k0 + (kv << 2)]);
                    *reinterpret_cast<ushort4*>(&lds_a[row * 40 + (kv << 2)]) = h;
                }
            } else {
                // stage A from X: 64x32 f32 -> bf16
                #pragma unroll
                for (int i = 0; i < 2; ++i) {
                    int idx = tid + (i << 8);
                    int row = idx >> 3, kv = idx & 7;
                    int gr = m0 + row;
                    float4 v = make_float4(0.f, 0.f, 0.f, 0.f);
                    if (gr < M) v = *reinterpret_cast<const float4*>(&X[((size_t)gr << 8) + k0 + (kv << 2)]);
                    ushort4 h;
                    h.x = f2bf(v.x); h.y = f2bf(v.y); h.z = f2bf(v.z); h.w = f2bf(v.w);
                    *reinterpret_cast<ushort4*>(&lds_a[row * 40 + (kv << 2)]) = h;
                }
            }
            // stage B: 128(n) x 32(k) bf16 (1024 ushort4, 4/thread)
            #pragma unroll
            for (int i = 0; i < 4; ++i) {
                int idx = tid + (i << 8);
                int n = idx >> 3, kv = idx & 7;
                ushort4 h = *reinterpret_cast<const ushort4*>(&Wb[(((size_t)(n0 + n)) << 8) + k0 + (kv << 2)]);
                *reinterpret_cast<ushort4*>(&lds_b[n * 40 + (kv << 2)]) = h;
            }
            __syncthreads();
            bf16x8 a = *reinterpret_cast<const bf16x8*>(&lds_a[(w * 16 + (lane & 15)) * 40 + ((lane >> 4) << 3)]);
            #pragma unroll
            for (int ni = 0; ni < 8; ++ni) {
                bf16x8 b = *reinterpret_cast<const bf16x8*>(&lds_b[(ni * 16 + (lane & 15)) * 40 + ((lane >> 4) << 3)]);
                acc[ni] = __builtin_amdgcn_mfma_f32_16x16x32_bf16(a, b, acc[ni], 0, 0, 0);
            }
            __syncthreads();
        }
    }
    // epilogue: C/D layout col=lane&15, row=(lane>>4)*4+reg
    const int rb = m0 + w * 16 + ((lane >> 4) << 2);
    const int cb = n0 + (lane & 15);
    #pragma unroll
    for (int ni = 0; ni < 8; ++ni) {
        int c = cb + ni * 16;
        #pragma unroll
        for (int j = 0; j < 4; ++j) {
            int r = rb + j;
            if (r < M) out[((size_t)r << 8) + c] = acc[ni][j] + bias[c];
        }
    }
}

extern "C" void kernel_launch(void* const* d_in, const int* in_sizes, int n_in,
                              void* d_out, int out_size, void* d_ws, size_t ws_size,
                              hipStream_t stream) {
    const float* x   = (const float*)d_in[0];
    const float* Wr  = (const float*)d_in[1];
    const float* W0w = (const float*)d_in[2];
    const float* W0b = (const float*)d_in[3];
    const int*   eidx= (const int*)d_in[4];
    const int*   et  = (const int*)d_in[5];
    const int N = in_sizes[0] / 256;      // nodes
    const int R = in_sizes[1] / 65536;    // relations
    const int E = in_sizes[5];            // edges
    const int* src = eidx;
    const int* dst = eidx + E;
    float* out = (float*)d_out;

    const int B = R * N;                  // bins
    const int NC = (B + 255) / 256;       // scan chunks (<=1024 required)

    // workspace layout
    char* ws = (char*)d_ws;
    size_t off = 0;
    auto alloc = [&](size_t bytes) { void* p = ws + off; off = (off + bytes + 255) & ~(size_t)255; return p; };
    int* deg    = (int*)alloc((size_t)B * 4);
    int* local  = (int*)alloc((size_t)B * 4);
    int* bsum   = (int*)alloc(4096);
    int* base   = (int*)alloc(4096);
    int* cursor = (int*)alloc((size_t)B * 4);
    int* srcs   = (int*)alloc((size_t)E * 4);
    unsigned short* Wt = (unsigned short*)alloc((size_t)(R + 1) * 65536 * 2);
    unsigned short* s  = (unsigned short*)alloc((size_t)B * 256 * 2);
    (void)ws_size;

    hipMemsetAsync(deg, 0, (size_t)B * 4, stream);
    hist_kernel<<<(E + 255) / 256, 256, 0, stream>>>(dst, et, deg, E, N);
    scan1_kernel<<<NC, 256, 0, stream>>>(deg, local, bsum, B);
    scan2_kernel<<<1, 1024, 0, stream>>>(bsum, base, NC);
    cursor_kernel<<<(B + 255) / 256, 256, 0, stream>>>(local, base, cursor, B);
    scatter_ids_kernel<<<(E + 255) / 256, 256, 0, stream>>>(src, dst, et, cursor, srcs, E, N);
    {
        int total = (R + 1) * 65536;
        wt_kernel<<<(total + 255) / 256, 256, 0, stream>>>(Wr, W0w, Wt, R);
    }
    reduce_kernel<<<(B + 3) / 4, 256, 0, stream>>>(x, srcs, deg, local, base, s, B);
    {
        dim3 grid((N + GBM - 1) / GBM, 256 / GBN);
        gemm_kernel<<<grid, 256, 0, stream>>>(s, x, Wt, W0b, out, N, R);
    }
}

// Round 3
// 183.133 us; speedup vs baseline: 6.9508x; 1.3980x over previous
//
#include <hip/hip_runtime.h>

typedef __bf16 bf16x8 __attribute__((ext_vector_type(8)));
typedef float f32x4 __attribute__((ext_vector_type(4)));

static __device__ __forceinline__ unsigned short f2bf(float f) {
    union { float f; unsigned int u; } v; v.f = f;
    unsigned int r = v.u + 0x7fffu + ((v.u >> 16) & 1u);
    return (unsigned short)(r >> 16);
}
static __device__ __forceinline__ float bf2f(unsigned short h) {
    union { unsigned int u; float f; } v; v.u = ((unsigned int)h) << 16;
    return v.f;
}

// ---- histogram: deg[et*N+dst]++ ----
__global__ void hist_kernel(const int* __restrict__ dst, const int* __restrict__ et,
                            int* __restrict__ deg, int E, int N) {
    int i = blockIdx.x * blockDim.x + threadIdx.x;
    if (i < E) atomicAdd(&deg[et[i] * N + dst[i]], 1);
}

// ---- 2-level exclusive scan over B bins (chunk=256) ----
__global__ void scan1_kernel(const int* __restrict__ deg, int* __restrict__ local,
                             int* __restrict__ bsum, int B) {
    __shared__ int tmp[256];
    int t = threadIdx.x, g = blockIdx.x * 256 + t;
    int v = (g < B) ? deg[g] : 0;
    tmp[t] = v; __syncthreads();
    for (int o = 1; o < 256; o <<= 1) {
        int u = (t >= o) ? tmp[t - o] : 0;
        __syncthreads();
        tmp[t] += u;
        __syncthreads();
    }
    if (g < B) local[g] = tmp[t] - v;
    if (t == 255) bsum[blockIdx.x] = tmp[t];
}

__global__ void scan2_kernel(const int* __restrict__ bsum, int* __restrict__ base, int nc) {
    __shared__ int tmp[1024];
    int t = threadIdx.x;
    int v = (t < nc) ? bsum[t] : 0;
    tmp[t] = v; __syncthreads();
    for (int o = 1; o < 1024; o <<= 1) {
        int u = (t >= o) ? tmp[t - o] : 0;
        __syncthreads();
        tmp[t] += u;
        __syncthreads();
    }
    if (t < nc) base[t] = tmp[t] - v;
}

__global__ void cursor_kernel(const int* __restrict__ local, const int* __restrict__ base,
                              int* __restrict__ cursor, int B) {
    int g = blockIdx.x * blockDim.x + threadIdx.x;
    if (g < B) cursor[g] = local[g] + base[g >> 8];
}

__global__ void scatter_ids_kernel(const int* __restrict__ src, const int* __restrict__ dst,
                                   const int* __restrict__ et, int* __restrict__ cursor,
                                   int* __restrict__ srcs, int E, int N) {
    int i = blockIdx.x * blockDim.x + threadIdx.x;
    if (i < E) {
        int b = et[i] * N + dst[i];
        int p = atomicAdd(&cursor[b], 1);
        srcs[p] = src[i];
    }
}

// ---- Wt2[o][sl*256+d] bf16: sl<16 -> Wr[sl][d][o]; sl==16 -> W0w[o][d] ----
// grid (17, 256), block 256: k = bx*256+tid (0..4351), o = by
__global__ void wt2_kernel(const float* __restrict__ Wr, const float* __restrict__ W0w,
                           unsigned short* __restrict__ Wt2) {
    int k = blockIdx.x * 256 + threadIdx.x;
    int o = blockIdx.y;
    int sl = k >> 8, d = k & 255;
    float v = (sl < 16) ? Wr[(((size_t)sl << 8) + d) * 256 + o]
                        : W0w[((size_t)o << 8) + d];
    Wt2[(size_t)o * 4352 + k] = f2bf(v);
}

// ---- x (f32) -> s slice 16 (bf16): s[n*4352 + 4096 + c] ----
__global__ void xbf_kernel(const float* __restrict__ x, unsigned short* __restrict__ s, int M) {
    int id = blockIdx.x * blockDim.x + threadIdx.x;
    if (id >= M * 64) return;
    int n = id >> 6, c4 = id & 63;
    float4 v = *reinterpret_cast<const float4*>(&x[((size_t)n << 8) + (c4 << 2)]);
    ushort4 h;
    h.x = f2bf(v.x); h.y = f2bf(v.y); h.z = f2bf(v.z); h.w = f2bf(v.w);
    *reinterpret_cast<ushort4*>(&s[(size_t)n * 4352 + 4096 + (c4 << 2)]) = h;
}

// ---- segment reduce: wave per (r,dst) bin; s[dn*17+r][:] = (sum_bf16 x rows)/cnt ----
__global__ void reduce_kernel(const int* __restrict__ srcs, const int* __restrict__ deg,
                              const int* __restrict__ local, const int* __restrict__ base,
                              unsigned short* __restrict__ s, int B, int N) {
    int wid = blockIdx.x * (blockDim.x >> 6) + (threadIdx.x >> 6);
    if (wid >= B) return;
    const int lane = threadIdx.x & 63;
    int cnt = deg[wid];
    float a0 = 0.f, a1 = 0.f, a2 = 0.f, a3 = 0.f;
    if (cnt > 0) {
        int st = local[wid] + base[wid >> 8];
        for (int i = 0; i < cnt; ++i) {
            int sn = srcs[st + i];
            ushort4 xv = *reinterpret_cast<const ushort4*>(&s[(size_t)sn * 4352 + 4096 + (lane << 2)]);
            a0 += bf2f(xv.x); a1 += bf2f(xv.y); a2 += bf2f(xv.z); a3 += bf2f(xv.w);
        }
        float sc = 1.0f / (float)cnt;
        a0 *= sc; a1 *= sc; a2 *= sc; a3 *= sc;
    }
    int r = wid / N, dn = wid - r * N;
    ushort4 h;
    h.x = f2bf(a0); h.y = f2bf(a1); h.z = f2bf(a2); h.w = f2bf(a3);
    *reinterpret_cast<ushort4*>(&s[((size_t)dn * 17 + r) * 256 + (lane << 2)]) = h;
}

// ---- dense GEMM: C[M,256] = A[M,4352](s,bf16) * B[256,4352](Wt2,bf16)^T ----
// tile 128x128, 256 thr (4 waves 2x2, each 64x64 = 4x4 frags of 16x16x32)
// BK=64, double-buffered LDS via global_load_lds + XOR swizzle + counted vmcnt
__global__ __launch_bounds__(256) void gemm_kernel(
    const unsigned short* __restrict__ S, const unsigned short* __restrict__ Wt2,
    const float* __restrict__ bias, float* __restrict__ dest,
    int M, int ksteps, int addbias)
{
    __shared__ __align__(16) unsigned short ldsA[2][8192];  // [buf][128 rows x 64 k]
    __shared__ __align__(16) unsigned short ldsB[2][8192];
    const int tid = threadIdx.x;
    const int lane = tid & 63, w = tid >> 6;
    const int wm = w & 1, wn = w >> 1;
    const int m0 = blockIdx.x * 128, n0 = blockIdx.y * 128;
    const int kstart = blockIdx.z * ksteps * 64;  // elements

    f32x4 acc[4][4] = {};

    // per-wave staging geometry: issue i covers flat = (w*4+i)*64 + lane
    const int flat_base = w * 4 * 64 + lane;

#define STAGE(buf, kstep)                                                                 \
    {                                                                                     \
        const int kb = (kstart + (kstep) * 64) * 2;                                       \
        _Pragma("unroll")                                                                 \
        for (int i = 0; i < 4; ++i) {                                                     \
            int flat = flat_base + i * 64;                                                \
            int row = flat >> 3, seg = flat & 7;                                          \
            int gr = m0 + row; gr = gr < M ? gr : M - 1;                                  \
            const char* gp = (const char*)S + (size_t)gr * 8704 + kb                      \
                             + ((seg * 16) ^ ((row & 7) << 4));                           \
            unsigned short* lp = &ldsA[buf][(w * 4 + i) * 512];                           \
            __builtin_amdgcn_global_load_lds(                                             \
                (const __attribute__((address_space(1))) void*)gp,                        \
                (__attribute__((address_space(3))) void*)lp, 16, 0, 0);                   \
        }                                                                                 \
        _Pragma("unroll")                                                                 \
        for (int i = 0; i < 4; ++i) {                                                     \
            int flat = flat_base + i * 64;                                                \
            int row = flat >> 3, seg = flat & 7;                                          \
            const char* gp = (const char*)Wt2 + (size_t)(n0 + row) * 8704 + kb            \
                             + ((seg * 16) ^ ((row & 7) << 4));                           \
            unsigned short* lp = &ldsB[buf][(w * 4 + i) * 512];                           \
            __builtin_amdgcn_global_load_lds(                                             \
                (const __attribute__((address_space(1))) void*)gp,                        \
                (__attribute__((address_space(3))) void*)lp, 16, 0, 0);                   \
        }                                                                                 \
    }

#define COMPUTE(buf)                                                                      \
    {                                                                                     \
        _Pragma("unroll")                                                                 \
        for (int kk = 0; kk < 2; ++kk) {                                                  \
            bf16x8 af[4], bfr[4];                                                         \
            _Pragma("unroll")                                                             \
            for (int m = 0; m < 4; ++m) {                                                 \
                int row = wm * 64 + m * 16 + (lane & 15);                                 \
                int colb = (kk * 64 + ((lane >> 4) << 4)) ^ ((row & 7) << 4);             \
                af[m] = *reinterpret_cast<const bf16x8*>(                                 \
                    (const char*)&ldsA[buf][0] + row * 128 + colb);                       \
            }                                                                             \
            _Pragma("unroll")                                                             \
            for (int n = 0; n < 4; ++n) {                                                 \
                int row = wn * 64 + n * 16 + (lane & 15);                                 \
                int colb = (kk * 64 + ((lane >> 4) << 4)) ^ ((row & 7) << 4);             \
                bfr[n] = *reinterpret_cast<const bf16x8*>(                                \
                    (const char*)&ldsB[buf][0] + row * 128 + colb);                       \
            }                                                                             \
            _Pragma("unroll")                                                             \
            for (int m = 0; m < 4; ++m)                                                   \
                _Pragma("unroll")                                                         \
                for (int n = 0; n < 4; ++n)                                               \
                    acc[m][n] = __builtin_amdgcn_mfma_f32_16x16x32_bf16(                  \
                        af[m], bfr[n], acc[m][n], 0, 0, 0);                               \
        }                                                                                 \
    }

    STAGE(0, 0)
    for (int t = 0; t < ksteps; ++t) {
        if (t + 1 < ksteps) {
            STAGE((t + 1) & 1, t + 1)
            asm volatile("s_waitcnt vmcnt(8)" ::: "memory");
        } else {
            asm volatile("s_waitcnt vmcnt(0)" ::: "memory");
        }
        __builtin_amdgcn_s_barrier();
        COMPUTE(t & 1)
        asm volatile("s_waitcnt lgkmcnt(0)" ::: "memory");
        __builtin_amdgcn_sched_barrier(0);
        __builtin_amdgcn_s_barrier();
    }
#undef STAGE
#undef COMPUTE

    // epilogue: C/D layout col=lane&15, row=(lane>>4)*4+j
    float* dst = dest + (size_t)blockIdx.z * M * 256;
    const int rbase = m0 + wm * 64 + ((lane >> 4) << 2);
    const int cbase = n0 + wn * 64 + (lane & 15);
    #pragma unroll
    for (int n = 0; n < 4; ++n) {
        int c = cbase + n * 16;
        float bv = addbias ? bias[c] : 0.0f;
        #pragma unroll
        for (int m = 0; m < 4; ++m) {
            #pragma unroll
            for (int j = 0; j < 4; ++j) {
                int r = rbase + m * 16 + j;
                if (r < M) dst[(size_t)r * 256 + c] = acc[m][n][j] + bv;
            }
        }
    }
}

// ---- combine split-K partials + bias ----
__global__ void combine_kernel(const float* __restrict__ pbuf, const float* __restrict__ bias,
                               float* __restrict__ out, int M, int KZ) {
    int id = blockIdx.x * blockDim.x + threadIdx.x;
    if (id >= M * 64) return;
    int n = id >> 6, c4 = id & 63;
    float4 a = *reinterpret_cast<const float4*>(&pbuf[((size_t)n << 8) + (c4 << 2)]);
    for (int kz = 1; kz < KZ; ++kz) {
        float4 b = *reinterpret_cast<const float4*>(&pbuf[(size_t)kz * M * 256 + ((size_t)n << 8) + (c4 << 2)]);
        a.x += b.x; a.y += b.y; a.z += b.z; a.w += b.w;
    }
    const float4 bv = *reinterpret_cast<const float4*>(&bias[c4 << 2]);
    a.x += bv.x; a.y += bv.y; a.z += bv.z; a.w += bv.w;
    *reinterpret_cast<float4*>(&out[((size_t)n << 8) + (c4 << 2)]) = a;
}

extern "C" void kernel_launch(void* const* d_in, const int* in_sizes, int n_in,
                              void* d_out, int out_size, void* d_ws, size_t ws_size,
                              hipStream_t stream) {
    const float* x   = (const float*)d_in[0];
    const float* Wr  = (const float*)d_in[1];
    const float* W0w = (const float*)d_in[2];
    const float* W0b = (const float*)d_in[3];
    const int*   eidx= (const int*)d_in[4];
    const int*   et  = (const int*)d_in[5];
    const int N = in_sizes[0] / 256;      // nodes (10000)
    const int R = in_sizes[1] / 65536;    // relations (16)
    const int E = in_sizes[5];            // edges (320000)
    const int* src = eidx;
    const int* dst = eidx + E;
    float* out = (float*)d_out;

    const int B = R * N;                  // bins
    const int NC = (B + 255) / 256;       // scan chunks (<=1024)
    const int K = (R + 1) * 256;          // 4352

    // ---- workspace layout: [region0 = max(pbuf, sortbufs)] [Wt2] [s] ----
    const size_t sz_pslice = (size_t)N * 256 * 4;                 // 10.24 MB
    const size_t sz_sort = (((size_t)B * 4 + 255) & ~255UL) * 3   // deg, local, cursor
                         + (((size_t)E * 4 + 255) & ~255UL)       // srcs
                         + 2 * 4096;                              // bsum, base
    const size_t sz_wt2 = (size_t)256 * K * 2;
    const size_t sz_s   = (size_t)N * K * 2;
    int KZ = 1;
    for (int kz = 4; kz >= 1; kz >>= 1) {
        size_t r0 = sz_sort > (size_t)kz * sz_pslice * (kz > 1) ? sz_sort : (kz > 1 ? (size_t)kz * sz_pslice : sz_sort);
        size_t need = ((r0 + 255) & ~255UL) + ((sz_wt2 + 255) & ~255UL) + sz_s + 1024;
        if (need <= ws_size || kz == 1) { KZ = kz; break; }
    }

    char* ws = (char*)d_ws;
    size_t off = 0;
    auto alloc = [&](size_t bytes) { void* p = ws + off; off = (off + bytes + 255) & ~(size_t)255; return p; };
    float* pbuf = (float*)ws;  // aliases sort bufs (sort dead before gemm)
    int* deg    = (int*)alloc((size_t)B * 4);
    int* local  = (int*)alloc((size_t)B * 4);
    int* bsum   = (int*)alloc(4096);
    int* base   = (int*)alloc(4096);
    int* cursor = (int*)alloc((size_t)B * 4);
    int* srcs   = (int*)alloc((size_t)E * 4);
    size_t region0 = (KZ > 1) ? (size_t)KZ * sz_pslice : 0;
    if (off > region0) region0 = off;
    off = (region0 + 255) & ~(size_t)255;
    unsigned short* Wt2 = (unsigned short*)alloc(sz_wt2);
    unsigned short* s   = (unsigned short*)alloc(sz_s);

    hipMemsetAsync(deg, 0, (size_t)B * 4, stream);
    hist_kernel<<<(E + 255) / 256, 256, 0, stream>>>(dst, et, deg, E, N);
    scan1_kernel<<<NC, 256, 0, stream>>>(deg, local, bsum, B);
    scan2_kernel<<<1, 1024, 0, stream>>>(bsum, base, NC);
    cursor_kernel<<<(B + 255) / 256, 256, 0, stream>>>(local, base, cursor, B);
    scatter_ids_kernel<<<(E + 255) / 256, 256, 0, stream>>>(src, dst, et, cursor, srcs, E, N);
    {
        dim3 g((K + 255) / 256, 256);
        wt2_kernel<<<g, 256, 0, stream>>>(Wr, W0w, Wt2);
    }
    xbf_kernel<<<(N * 64 + 255) / 256, 256, 0, stream>>>(x, s, N);
    reduce_kernel<<<(B + 3) / 4, 256, 0, stream>>>(srcs, deg, local, base, s, B, N);
    {
        const int ktot = K / 64;                  // 68
        const int ksteps = ktot / KZ;             // 68/KZ (exact for 1,2,4)
        dim3 grid((N + 127) / 128, 2, KZ);
        if (KZ == 1) {
            gemm_kernel<<<grid, 256, 0, stream>>>(s, Wt2, W0b, out, N, ksteps, 1);
        } else {
            gemm_kernel<<<grid, 256, 0, stream>>>(s, Wt2, W0b, pbuf, N, ksteps, 0);
            combine_kernel<<<(N * 64 + 255) / 256, 256, 0, stream>>>(pbuf, W0b, out, N, KZ);
        }
    }
}

// Round 4
// 157.782 us; speedup vs baseline: 8.0676x; 1.1607x over previous
//
#include <hip/hip_runtime.h>

typedef __bf16 bf16x8 __attribute__((ext_vector_type(8)));
typedef float f32x4 __attribute__((ext_vector_type(4)));

static __device__ __forceinline__ unsigned short f2bf(float f) {
    union { float f; unsigned int u; } v; v.f = f;
    unsigned int r = v.u + 0x7fffu + ((v.u >> 16) & 1u);
    return (unsigned short)(r >> 16);
}
static __device__ __forceinline__ float blo(unsigned int u) {
    union { unsigned int u; float f; } v; v.u = u << 16; return v.f;
}
static __device__ __forceinline__ float bhi(unsigned int u) {
    union { unsigned int u; float f; } v; v.u = u & 0xffff0000u; return v.f;
}
static __device__ __forceinline__ unsigned int pack2(float a, float b) {
    return (unsigned int)f2bf(a) | ((unsigned int)f2bf(b) << 16);
}

// ---- histogram: deg[et*N+dst]++ ----
__global__ void hist_kernel(const int* __restrict__ dst, const int* __restrict__ et,
                            int* __restrict__ deg, int E, int N) {
    int i = blockIdx.x * blockDim.x + threadIdx.x;
    if (i < E) atomicAdd(&deg[et[i] * N + dst[i]], 1);
}

// ---- 2-level exclusive scan over B bins (chunk=256); also zero ctr ----
__global__ void scan1_kernel(const int* __restrict__ deg, int* __restrict__ local,
                             int* __restrict__ bsum, int* __restrict__ ctr, int B) {
    __shared__ int tmp[256];
    int t = threadIdx.x, g = blockIdx.x * 256 + t;
    int v = (g < B) ? deg[g] : 0;
    tmp[t] = v; __syncthreads();
    for (int o = 1; o < 256; o <<= 1) {
        int u = (t >= o) ? tmp[t - o] : 0;
        __syncthreads();
        tmp[t] += u;
        __syncthreads();
    }
    if (g < B) { local[g] = tmp[t] - v; ctr[g] = 0; }
    if (t == 255) bsum[blockIdx.x] = tmp[t];
}

__global__ void scan2_kernel(const int* __restrict__ bsum, int* __restrict__ base, int nc) {
    __shared__ int tmp[1024];
    int t = threadIdx.x;
    int v = (t < nc) ? bsum[t] : 0;
    tmp[t] = v; __syncthreads();
    for (int o = 1; o < 1024; o <<= 1) {
        int u = (t >= o) ? tmp[t - o] : 0;
        __syncthreads();
        tmp[t] += u;
        __syncthreads();
    }
    if (t < nc) base[t] = tmp[t] - v;
}

// ---- bucket edges: pos = local+base+ctr++ ----
__global__ void scatter_ids_kernel(const int* __restrict__ src, const int* __restrict__ dst,
                                   const int* __restrict__ et, const int* __restrict__ local,
                                   const int* __restrict__ base, int* __restrict__ ctr,
                                   int* __restrict__ srcs, int E, int N) {
    int i = blockIdx.x * blockDim.x + threadIdx.x;
    if (i < E) {
        int b = et[i] * N + dst[i];
        int p = local[b] + base[b >> 8] + atomicAdd(&ctr[b], 1);
        srcs[p] = src[i];
    }
}

// ---- Wt2[o][sl*256+d] bf16: sl<16 -> Wr[sl][d][o]; sl==16 -> W0w[o][d] ----
__global__ void wt2_kernel(const float* __restrict__ Wr, const float* __restrict__ W0w,
                           unsigned short* __restrict__ Wt2) {
    int k = blockIdx.x * 256 + threadIdx.x;
    int o = blockIdx.y;
    int sl = k >> 8, d = k & 255;
    float v = (sl < 16) ? Wr[(((size_t)sl << 8) + d) * 256 + o]
                        : W0w[((size_t)o << 8) + d];
    Wt2[(size_t)o * 4352 + k] = f2bf(v);
}

// ---- x (f32) -> s slice 16 (bf16): s[n*4352 + 4096 + c] ----
__global__ void xbf_kernel(const float* __restrict__ x, unsigned short* __restrict__ s, int M) {
    int id = blockIdx.x * blockDim.x + threadIdx.x;
    if (id >= M * 64) return;
    int n = id >> 6, c4 = id & 63;
    float4 v = *reinterpret_cast<const float4*>(&x[((size_t)n << 8) + (c4 << 2)]);
    ushort4 h;
    h.x = f2bf(v.x); h.y = f2bf(v.y); h.z = f2bf(v.z); h.w = f2bf(v.w);
    *reinterpret_cast<ushort4*>(&s[(size_t)n * 4352 + 4096 + (c4 << 2)]) = h;
}

// ---- segment reduce: half-wave (32 lanes x 16B) per (r,dn) bin; 2 bins/wave ----
// s[dn*17+r][:] = (sum over edges of bf16(x[src])) / cnt
__global__ __launch_bounds__(256) void reduce_kernel(
    const int* __restrict__ srcs, const int* __restrict__ deg,
    const int* __restrict__ local, const int* __restrict__ base,
    unsigned short* __restrict__ s, int N)
{
    const int r = blockIdx.y;
    const int dn = blockIdx.x * 8 + (threadIdx.x >> 5);
    if (dn >= N) return;
    const int lane = threadIdx.x & 31;
    const int bin = r * N + dn;
    const int cnt = deg[bin];
    const int st  = local[bin] + base[bin >> 8];

    float a0 = 0.f, a1 = 0.f, a2 = 0.f, a3 = 0.f;
    float a4 = 0.f, a5 = 0.f, a6 = 0.f, a7 = 0.f;
    for (int c0 = 0; c0 < cnt; c0 += 32) {
        int sv = 0;
        if (c0 + lane < cnt) sv = srcs[st + c0 + lane];
        int m = cnt - c0; if (m > 32) m = 32;
        for (int i = 0; i < m; ++i) {
            int sn = __shfl(sv, i, 32);
            const uint4 v = *reinterpret_cast<const uint4*>(
                &s[(size_t)sn * 4352 + 4096 + (lane << 3)]);
            a0 += blo(v.x); a1 += bhi(v.x);
            a2 += blo(v.y); a3 += bhi(v.y);
            a4 += blo(v.z); a5 += bhi(v.z);
            a6 += blo(v.w); a7 += bhi(v.w);
        }
    }
    if (cnt > 0) {
        float sc = 1.0f / (float)cnt;
        a0 *= sc; a1 *= sc; a2 *= sc; a3 *= sc;
        a4 *= sc; a5 *= sc; a6 *= sc; a7 *= sc;
    }
    uint4 o;
    o.x = pack2(a0, a1); o.y = pack2(a2, a3);
    o.z = pack2(a4, a5); o.w = pack2(a6, a7);
    *reinterpret_cast<uint4*>(&s[((size_t)dn * 17 + r) * 256 + (lane << 3)]) = o;
}

// ---- dense GEMM: C[M,256] = A[M,4352](s,bf16) * B[256,4352](Wt2,bf16)^T ----
// tile 128x128, 256 thr (4 waves 2x2, each 64x64 = 4x4 frags of 16x16x32)
// BK=64, double-buffered LDS via global_load_lds + XOR swizzle + counted vmcnt
__global__ __launch_bounds__(256) void gemm_kernel(
    const unsigned short* __restrict__ S, const unsigned short* __restrict__ Wt2,
    const float* __restrict__ bias, float* __restrict__ dest,
    int M, int ksteps, int addbias)
{
    __shared__ __align__(16) unsigned short ldsA[2][8192];  // [buf][128 rows x 64 k]
    __shared__ __align__(16) unsigned short ldsB[2][8192];
    const int tid = threadIdx.x;
    const int lane = tid & 63, w = tid >> 6;
    const int wm = w & 1, wn = w >> 1;
    const int m0 = blockIdx.x * 128, n0 = blockIdx.y * 128;
    const int kstart = blockIdx.z * ksteps * 64;  // elements

    f32x4 acc[4][4] = {};

    const int flat_base = w * 4 * 64 + lane;

#define STAGE(buf, kstep)                                                                 \
    {                                                                                     \
        const int kb = (kstart + (kstep) * 64) * 2;                                       \
        _Pragma("unroll")                                                                 \
        for (int i = 0; i < 4; ++i) {                                                     \
            int flat = flat_base + i * 64;                                                \
            int row = flat >> 3, seg = flat & 7;                                          \
            int gr = m0 + row; gr = gr < M ? gr : M - 1;                                  \
            const char* gp = (const char*)S + (size_t)gr * 8704 + kb                      \
                             + ((seg * 16) ^ ((row & 7) << 4));                           \
            unsigned short* lp = &ldsA[buf][(w * 4 + i) * 512];                           \
            __builtin_amdgcn_global_load_lds(                                             \
                (const __attribute__((address_space(1))) void*)gp,                        \
                (__attribute__((address_space(3))) void*)lp, 16, 0, 0);                   \
        }                                                                                 \
        _Pragma("unroll")                                                                 \
        for (int i = 0; i < 4; ++i) {                                                     \
            int flat = flat_base + i * 64;                                                \
            int row = flat >> 3, seg = flat & 7;                                          \
            const char* gp = (const char*)Wt2 + (size_t)(n0 + row) * 8704 + kb            \
                             + ((seg * 16) ^ ((row & 7) << 4));                           \
            unsigned short* lp = &ldsB[buf][(w * 4 + i) * 512];                           \
            __builtin_amdgcn_global_load_lds(                                             \
                (const __attribute__((address_space(1))) void*)gp,                        \
                (__attribute__((address_space(3))) void*)lp, 16, 0, 0);                   \
        }                                                                                 \
    }

#define COMPUTE(buf)                                                                      \
    {                                                                                     \
        _Pragma("unroll")                                                                 \
        for (int kk = 0; kk < 2; ++kk) {                                                  \
            bf16x8 af[4], bfr[4];                                                         \
            _Pragma("unroll")                                                             \
            for (int m = 0; m < 4; ++m) {                                                 \
                int row = wm * 64 + m * 16 + (lane & 15);                                 \
                int colb = (kk * 64 + ((lane >> 4) << 4)) ^ ((row & 7) << 4);             \
                af[m] = *reinterpret_cast<const bf16x8*>(                                 \
                    (const char*)&ldsA[buf][0] + row * 128 + colb);                       \
            }                                                                             \
            _Pragma("unroll")                                                             \
            for (int n = 0; n < 4; ++n) {                                                 \
                int row = wn * 64 + n * 16 + (lane & 15);                                 \
                int colb = (kk * 64 + ((lane >> 4) << 4)) ^ ((row & 7) << 4);             \
                bfr[n] = *reinterpret_cast<const bf16x8*>(                                \
                    (const char*)&ldsB[buf][0] + row * 128 + colb);                       \
            }                                                                             \
            _Pragma("unroll")                                                             \
            for (int m = 0; m < 4; ++m)                                                   \
                _Pragma("unroll")                                                         \
                for (int n = 0; n < 4; ++n)                                               \
                    acc[m][n] = __builtin_amdgcn_mfma_f32_16x16x32_bf16(                  \
                        af[m], bfr[n], acc[m][n], 0, 0, 0);                               \
        }                                                                                 \
    }

    STAGE(0, 0)
    for (int t = 0; t < ksteps; ++t) {
        if (t + 1 < ksteps) {
            STAGE((t + 1) & 1, t + 1)
            asm volatile("s_waitcnt vmcnt(8)" ::: "memory");
        } else {
            asm volatile("s_waitcnt vmcnt(0)" ::: "memory");
        }
        __builtin_amdgcn_s_barrier();
        COMPUTE(t & 1)
        asm volatile("s_waitcnt lgkmcnt(0)" ::: "memory");
        __builtin_amdgcn_sched_barrier(0);
        __builtin_amdgcn_s_barrier();
    }
#undef STAGE
#undef COMPUTE

    float* dst = dest + (size_t)blockIdx.z * M * 256;
    const int rbase = m0 + wm * 64 + ((lane >> 4) << 2);
    const int cbase = n0 + wn * 64 + (lane & 15);
    #pragma unroll
    for (int n = 0; n < 4; ++n) {
        int c = cbase + n * 16;
        float bv = addbias ? bias[c] : 0.0f;
        #pragma unroll
        for (int m = 0; m < 4; ++m) {
            #pragma unroll
            for (int j = 0; j < 4; ++j) {
                int r = rbase + m * 16 + j;
                if (r < M) dst[(size_t)r * 256 + c] = acc[m][n][j] + bv;
            }
        }
    }
}

// ---- combine split-K partials + bias ----
__global__ void combine_kernel(const float* __restrict__ pbuf, const float* __restrict__ bias,
                               float* __restrict__ out, int M, int KZ) {
    int id = blockIdx.x * blockDim.x + threadIdx.x;
    if (id >= M * 64) return;
    int n = id >> 6, c4 = id & 63;
    float4 a = *reinterpret_cast<const float4*>(&pbuf[((size_t)n << 8) + (c4 << 2)]);
    for (int kz = 1; kz < KZ; ++kz) {
        float4 b = *reinterpret_cast<const float4*>(&pbuf[(size_t)kz * M * 256 + ((size_t)n << 8) + (c4 << 2)]);
        a.x += b.x; a.y += b.y; a.z += b.z; a.w += b.w;
    }
    const float4 bv = *reinterpret_cast<const float4*>(&bias[c4 << 2]);
    a.x += bv.x; a.y += bv.y; a.z += bv.z; a.w += bv.w;
    *reinterpret_cast<float4*>(&out[((size_t)n << 8) + (c4 << 2)]) = a;
}

extern "C" void kernel_launch(void* const* d_in, const int* in_sizes, int n_in,
                              void* d_out, int out_size, void* d_ws, size_t ws_size,
                              hipStream_t stream) {
    const float* x   = (const float*)d_in[0];
    const float* Wr  = (const float*)d_in[1];
    const float* W0w = (const float*)d_in[2];
    const float* W0b = (const float*)d_in[3];
    const int*   eidx= (const int*)d_in[4];
    const int*   et  = (const int*)d_in[5];
    const int N = in_sizes[0] / 256;      // nodes (10000)
    const int R = in_sizes[1] / 65536;    // relations (16)
    const int E = in_sizes[5];            // edges (320000)
    const int* src = eidx;
    const int* dst = eidx + E;
    float* out = (float*)d_out;

    const int B = R * N;                  // bins
    const int NC = (B + 255) / 256;       // scan chunks (<=1024)
    const int K = (R + 1) * 256;          // 4352

    // ---- workspace layout: [region0 = max(pbuf, sortbufs)] [Wt2] [s] ----
    const size_t sz_pslice = (size_t)N * 256 * 4;
    const size_t sz_sort = (((size_t)B * 4 + 255) & ~255UL) * 3   // deg, local, ctr
                         + (((size_t)E * 4 + 255) & ~255UL)       // srcs
                         + 2 * 4096;                              // bsum, base
    const size_t sz_wt2 = (size_t)256 * K * 2;
    const size_t sz_s   = (size_t)N * K * 2;
    int KZ = 1;
    for (int kz = 4; kz >= 1; kz >>= 1) {
        size_t r0 = (kz > 1) ? (size_t)kz * sz_pslice : 0;
        if (sz_sort > r0) r0 = sz_sort;
        size_t need = ((r0 + 255) & ~255UL) + ((sz_wt2 + 255) & ~255UL) + sz_s + 1024;
        if (need <= ws_size || kz == 1) { KZ = kz; break; }
    }

    char* ws = (char*)d_ws;
    size_t off = 0;
    auto alloc = [&](size_t bytes) { void* p = ws + off; off = (off + bytes + 255) & ~(size_t)255; return p; };
    float* pbuf = (float*)ws;  // aliases sort bufs (sort dead before gemm)
    int* deg    = (int*)alloc((size_t)B * 4);
    int* local  = (int*)alloc((size_t)B * 4);
    int* bsum   = (int*)alloc(4096);
    int* base   = (int*)alloc(4096);
    int* ctr    = (int*)alloc((size_t)B * 4);
    int* srcs   = (int*)alloc((size_t)E * 4);
    size_t region0 = (KZ > 1) ? (size_t)KZ * sz_pslice : 0;
    if (off > region0) region0 = off;
    off = (region0 + 255) & ~(size_t)255;
    unsigned short* Wt2 = (unsigned short*)alloc(sz_wt2);
    unsigned short* s   = (unsigned short*)alloc(sz_s);

    hipMemsetAsync(deg, 0, (size_t)B * 4, stream);
    hist_kernel<<<(E + 255) / 256, 256, 0, stream>>>(dst, et, deg, E, N);
    scan1_kernel<<<NC, 256, 0, stream>>>(deg, local, bsum, ctr, B);
    scan2_kernel<<<1, 1024, 0, stream>>>(bsum, base, NC);
    scatter_ids_kernel<<<(E + 255) / 256, 256, 0, stream>>>(src, dst, et, local, base, ctr, srcs, E, N);
    {
        dim3 g((K + 255) / 256, 256);
        wt2_kernel<<<g, 256, 0, stream>>>(Wr, W0w, Wt2);
    }
    xbf_kernel<<<(N * 64 + 255) / 256, 256, 0, stream>>>(x, s, N);
    {
        dim3 g((N + 7) / 8, R);
        reduce_kernel<<<g, 256, 0, stream>>>(srcs, deg, local, base, s, N);
    }
    {
        const int ktot = K / 64;                  // 68
        const int ksteps = ktot / KZ;
        dim3 grid((N + 127) / 128, 2, KZ);
        if (KZ == 1) {
            gemm_kernel<<<grid, 256, 0, stream>>>(s, Wt2, W0b, out, N, ksteps, 1);
        } else {
            gemm_kernel<<<grid, 256, 0, stream>>>(s, Wt2, W0b, pbuf, N, ksteps, 0);
            combine_kernel<<<(N * 64 + 255) / 256, 256, 0, stream>>>(pbuf, W0b, out, N, KZ);
        }
    }
}

// Round 5
// 136.048 us; speedup vs baseline: 9.3564x; 1.1598x over previous
//
#include <hip/hip_runtime.h>

typedef __bf16 bf16x8 __attribute__((ext_vector_type(8)));
typedef float f32x4 __attribute__((ext_vector_type(4)));

static __device__ __forceinline__ unsigned short f2bf(float f) {
    union { float f; unsigned int u; } v; v.f = f;
    unsigned int r = v.u + 0x7fffu + ((v.u >> 16) & 1u);
    return (unsigned short)(r >> 16);
}
static __device__ __forceinline__ float blo(unsigned int u) {
    union { unsigned int u; float f; } v; v.u = u << 16; return v.f;
}
static __device__ __forceinline__ float bhi(unsigned int u) {
    union { unsigned int u; float f; } v; v.u = u & 0xffff0000u; return v.f;
}
static __device__ __forceinline__ unsigned int pack2(float a, float b) {
    return (unsigned int)f2bf(a) | ((unsigned int)f2bf(b) << 16);
}

// ---- fused prep: [0,nh) hist | [nh,nh+nw) Wt2 build | [nh+nw,..) x->bf16 slice ----
__global__ void prep_kernel(const int* __restrict__ dst, const int* __restrict__ et,
                            int* __restrict__ deg,
                            const float* __restrict__ Wr, const float* __restrict__ W0w,
                            unsigned short* __restrict__ Wt2,
                            const float* __restrict__ x, unsigned short* __restrict__ s,
                            int E, int N, int R, int nh, int nw) {
    const int bid = blockIdx.x, tid = threadIdx.x;
    const int K = (R + 1) * 256;
    if (bid < nh) {
        int i = bid * 256 + tid;
        if (i < E) atomicAdd(&deg[et[i] * N + dst[i]], 1);
    } else if (bid < nh + nw) {
        int t = bid - nh;
        int o = t / (R + 1), kb = t - o * (R + 1);
        float v = (kb < R) ? Wr[(((size_t)kb << 8) + tid) * 256 + o]
                           : W0w[((size_t)o << 8) + tid];
        Wt2[(size_t)o * K + (kb << 8) + tid] = f2bf(v);
    } else {
        int id = (bid - nh - nw) * 256 + tid;
        int n = id >> 6, c4 = id & 63;
        if (n < N) {
            float4 v = *reinterpret_cast<const float4*>(&x[((size_t)n << 8) + (c4 << 2)]);
            ushort4 h;
            h.x = f2bf(v.x); h.y = f2bf(v.y); h.z = f2bf(v.z); h.w = f2bf(v.w);
            *reinterpret_cast<ushort4*>(&s[(size_t)n * K + (K - 256) + (c4 << 2)]) = h;
        }
    }
}

// ---- 2-level exclusive scan over B bins (chunk=256); also zero ctr ----
__global__ void scan1_kernel(const int* __restrict__ deg, int* __restrict__ local,
                             int* __restrict__ bsum, int* __restrict__ ctr, int B) {
    __shared__ int tmp[256];
    int t = threadIdx.x, g = blockIdx.x * 256 + t;
    int v = (g < B) ? deg[g] : 0;
    tmp[t] = v; __syncthreads();
    for (int o = 1; o < 256; o <<= 1) {
        int u = (t >= o) ? tmp[t - o] : 0;
        __syncthreads();
        tmp[t] += u;
        __syncthreads();
    }
    if (g < B) { local[g] = tmp[t] - v; ctr[g] = 0; }
    if (t == 255) bsum[blockIdx.x] = tmp[t];
}

__global__ void scan2_kernel(const int* __restrict__ bsum, int* __restrict__ base, int nc) {
    __shared__ int tmp[1024];
    int t = threadIdx.x;
    int v = (t < nc) ? bsum[t] : 0;
    tmp[t] = v; __syncthreads();
    for (int o = 1; o < 1024; o <<= 1) {
        int u = (t >= o) ? tmp[t - o] : 0;
        __syncthreads();
        tmp[t] += u;
        __syncthreads();
    }
    if (t < nc) base[t] = tmp[t] - v;
}

// ---- bucket edges: pos = local+base+ctr++ ----
__global__ void scatter_ids_kernel(const int* __restrict__ src, const int* __restrict__ dst,
                                   const int* __restrict__ et, const int* __restrict__ local,
                                   const int* __restrict__ base, int* __restrict__ ctr,
                                   int* __restrict__ srcs, int E, int N) {
    int i = blockIdx.x * blockDim.x + threadIdx.x;
    if (i < E) {
        int b = et[i] * N + dst[i];
        int p = local[b] + base[b >> 8] + atomicAdd(&ctr[b], 1);
        srcs[p] = src[i];
    }
}

// ---- segment reduce: half-wave (32 lanes x 16B) per (r,dn) bin; 2 bins/wave ----
__global__ __launch_bounds__(256) void reduce_kernel(
    const int* __restrict__ srcs, const int* __restrict__ deg,
    const int* __restrict__ local, const int* __restrict__ base,
    unsigned short* __restrict__ s, int N, int R)
{
    const int K = (R + 1) * 256;
    const int r = blockIdx.y;
    const int dn = blockIdx.x * 8 + (threadIdx.x >> 5);
    if (dn >= N) return;
    const int lane = threadIdx.x & 31;
    const int bin = r * N + dn;
    const int cnt = deg[bin];
    const int st  = local[bin] + base[bin >> 8];

    float a0 = 0.f, a1 = 0.f, a2 = 0.f, a3 = 0.f;
    float a4 = 0.f, a5 = 0.f, a6 = 0.f, a7 = 0.f;
    for (int c0 = 0; c0 < cnt; c0 += 32) {
        int sv = 0;
        if (c0 + lane < cnt) sv = srcs[st + c0 + lane];
        int m = cnt - c0; if (m > 32) m = 32;
        for (int i = 0; i < m; ++i) {
            int sn = __shfl(sv, i, 32);
            const uint4 v = *reinterpret_cast<const uint4*>(
                &s[(size_t)sn * K + (K - 256) + (lane << 3)]);
            a0 += blo(v.x); a1 += bhi(v.x);
            a2 += blo(v.y); a3 += bhi(v.y);
            a4 += blo(v.z); a5 += bhi(v.z);
            a6 += blo(v.w); a7 += bhi(v.w);
        }
    }
    if (cnt > 0) {
        float sc = 1.0f / (float)cnt;
        a0 *= sc; a1 *= sc; a2 *= sc; a3 *= sc;
        a4 *= sc; a5 *= sc; a6 *= sc; a7 *= sc;
    }
    uint4 o;
    o.x = pack2(a0, a1); o.y = pack2(a2, a3);
    o.z = pack2(a4, a5); o.w = pack2(a6, a7);
    *reinterpret_cast<uint4*>(&s[(size_t)dn * K + (r << 8) + (lane << 3)]) = o;
}

// ---- dense GEMM: C[M,256] = A[M,K](s,bf16) * B[256,K](Wt2,bf16)^T ----
// tile 128x128, 256 thr (4 waves 2x2, each 64x64 = 4x4 frags of 16x16x32)
// BK=64; A double-buffered (issued 2 steps ahead), B single-buffered (L2-hot);
// global_load_lds + XOR swizzle + counted vmcnt(4); LDS 48KB -> 3 blocks/CU
__global__ __launch_bounds__(256) void gemm_kernel(
    const unsigned short* __restrict__ S, const unsigned short* __restrict__ Wt2,
    const float* __restrict__ bias, float* __restrict__ dest,
    int M, int K, int ksteps, int addbias)
{
    __shared__ __align__(16) unsigned short ldsA[2][8192];  // 2 x 128 rows x 64 k
    __shared__ __align__(16) unsigned short ldsB[8192];     // 128 rows x 64 k
    const int tid = threadIdx.x;
    const int lane = tid & 63, w = tid >> 6;
    const int wm = w & 1, wn = w >> 1;
    const int m0 = blockIdx.x * 128, n0 = blockIdx.y * 128;
    const int kstart = blockIdx.z * ksteps * 64;  // elements
    const size_t rowb = (size_t)K * 2;            // row bytes

    f32x4 acc[4][4] = {};

    const int flat_base = w * 4 * 64 + lane;

#define STAGE_A(buf, kstep)                                                               \
    {                                                                                     \
        const int kb = (kstart + (kstep) * 64) * 2;                                       \
        _Pragma("unroll")                                                                 \
        for (int i = 0; i < 4; ++i) {                                                     \
            int flat = flat_base + i * 64;                                                \
            int row = flat >> 3, seg = flat & 7;                                          \
            int gr = m0 + row; gr = gr < M ? gr : M - 1;                                  \
            const char* gp = (const char*)S + (size_t)gr * rowb + kb                      \
                             + ((seg * 16) ^ ((row & 7) << 4));                           \
            unsigned short* lp = &ldsA[buf][(w * 4 + i) * 512];                           \
            __builtin_amdgcn_global_load_lds(                                             \
                (const __attribute__((address_space(1))) void*)gp,                        \
                (__attribute__((address_space(3))) void*)lp, 16, 0, 0);                   \
        }                                                                                 \
    }

#define STAGE_B(kstep)                                                                    \
    {                                                                                     \
        const int kb = (kstart + (kstep) * 64) * 2;                                       \
        _Pragma("unroll")                                                                 \
        for (int i = 0; i < 4; ++i) {                                                     \
            int flat = flat_base + i * 64;                                                \
            int row = flat >> 3, seg = flat & 7;                                          \
            const char* gp = (const char*)Wt2 + (size_t)(n0 + row) * rowb + kb            \
                             + ((seg * 16) ^ ((row & 7) << 4));                           \
            unsigned short* lp = &ldsB[(w * 4 + i) * 512];                                \
            __builtin_amdgcn_global_load_lds(                                             \
                (const __attribute__((address_space(1))) void*)gp,                        \
                (__attribute__((address_space(3))) void*)lp, 16, 0, 0);                   \
        }                                                                                 \
    }

#define COMPUTE(buf)                                                                      \
    {                                                                                     \
        _Pragma("unroll")                                                                 \
        for (int kk = 0; kk < 2; ++kk) {                                                  \
            bf16x8 af[4], bfr[4];                                                         \
            _Pragma("unroll")                                                             \
            for (int m = 0; m < 4; ++m) {                                                 \
                int row = wm * 64 + m * 16 + (lane & 15);                                 \
                int colb = (kk * 64 + ((lane >> 4) << 4)) ^ ((row & 7) << 4);             \
                af[m] = *reinterpret_cast<const bf16x8*>(                                 \
                    (const char*)&ldsA[buf][0] + row * 128 + colb);                       \
            }                                                                             \
            _Pragma("unroll")                                                             \
            for (int n = 0; n < 4; ++n) {                                                 \
                int row = wn * 64 + n * 16 + (lane & 15);                                 \
                int colb = (kk * 64 + ((lane >> 4) << 4)) ^ ((row & 7) << 4);             \
                bfr[n] = *reinterpret_cast<const bf16x8*>(                                \
                    (const char*)&ldsB[0] + row * 128 + colb);                            \
            }                                                                             \
            __builtin_amdgcn_s_setprio(1);                                                \
            _Pragma("unroll")                                                             \
            for (int m = 0; m < 4; ++m)                                                   \
                _Pragma("unroll")                                                         \
                for (int n = 0; n < 4; ++n)                                               \
                    acc[m][n] = __builtin_amdgcn_mfma_f32_16x16x32_bf16(                  \
                        af[m], bfr[n], acc[m][n], 0, 0, 0);                               \
            __builtin_amdgcn_s_setprio(0);                                                \
        }                                                                                 \
    }

    // prologue (requires ksteps >= 2): A0, B0, A1 in flight; drain to A1
    STAGE_A(0, 0)
    STAGE_B(0)
    STAGE_A(1, 1)
    asm volatile("s_waitcnt vmcnt(4)" ::: "memory");
    __builtin_amdgcn_s_barrier();

    for (int t = 0; t < ksteps; ++t) {
        COMPUTE(t & 1)
        asm volatile("s_waitcnt lgkmcnt(0)" ::: "memory");
        __builtin_amdgcn_sched_barrier(0);
        __builtin_amdgcn_s_barrier();
        if (t + 1 < ksteps) {
            STAGE_B(t + 1)
            if (t + 2 < ksteps) {
                STAGE_A(t & 1, t + 2)
                asm volatile("s_waitcnt vmcnt(4)" ::: "memory");
            } else {
                asm volatile("s_waitcnt vmcnt(0)" ::: "memory");
            }
            __builtin_amdgcn_s_barrier();
        }
    }
#undef STAGE_A
#undef STAGE_B
#undef COMPUTE

    float* dst = dest + (size_t)blockIdx.z * M * 256;
    const int rbase = m0 + wm * 64 + ((lane >> 4) << 2);
    const int cbase = n0 + wn * 64 + (lane & 15);
    #pragma unroll
    for (int n = 0; n < 4; ++n) {
        int c = cbase + n * 16;
        float bv = addbias ? bias[c] : 0.0f;
        #pragma unroll
        for (int m = 0; m < 4; ++m) {
            #pragma unroll
            for (int j = 0; j < 4; ++j) {
                int r = rbase + m * 16 + j;
                if (r < M) dst[(size_t)r * 256 + c] = acc[m][n][j] + bv;
            }
        }
    }
}

// ---- combine split-K partials + bias ----
__global__ void combine_kernel(const float* __restrict__ pbuf, const float* __restrict__ bias,
                               float* __restrict__ out, int M, int KZ) {
    int id = blockIdx.x * blockDim.x + threadIdx.x;
    if (id >= M * 64) return;
    int n = id >> 6, c4 = id & 63;
    float4 a = *reinterpret_cast<const float4*>(&pbuf[((size_t)n << 8) + (c4 << 2)]);
    for (int kz = 1; kz < KZ; ++kz) {
        float4 b = *reinterpret_cast<const float4*>(&pbuf[(size_t)kz * M * 256 + ((size_t)n << 8) + (c4 << 2)]);
        a.x += b.x; a.y += b.y; a.z += b.z; a.w += b.w;
    }
    const float4 bv = *reinterpret_cast<const float4*>(&bias[c4 << 2]);
    a.x += bv.x; a.y += bv.y; a.z += bv.z; a.w += bv.w;
    *reinterpret_cast<float4*>(&out[((size_t)n << 8) + (c4 << 2)]) = a;
}

extern "C" void kernel_launch(void* const* d_in, const int* in_sizes, int n_in,
                              void* d_out, int out_size, void* d_ws, size_t ws_size,
                              hipStream_t stream) {
    const float* x   = (const float*)d_in[0];
    const float* Wr  = (const float*)d_in[1];
    const float* W0w = (const float*)d_in[2];
    const float* W0b = (const float*)d_in[3];
    const int*   eidx= (const int*)d_in[4];
    const int*   et  = (const int*)d_in[5];
    const int N = in_sizes[0] / 256;      // nodes (10000)
    const int R = in_sizes[1] / 65536;    // relations (16)
    const int E = in_sizes[5];            // edges (320000)
    const int* src = eidx;
    const int* dst = eidx + E;
    float* out = (float*)d_out;

    const int B = R * N;                  // bins
    const int NC = (B + 255) / 256;       // scan chunks (<=1024)
    const int K = (R + 1) * 256;          // 4352

    // ---- workspace layout: [region0 = max(pbuf, sortbufs)] [Wt2] [s] ----
    const size_t sz_pslice = (size_t)N * 256 * 4;
    const size_t sz_sort = (((size_t)B * 4 + 255) & ~255UL) * 3   // deg, local, ctr
                         + (((size_t)E * 4 + 255) & ~255UL)       // srcs
                         + 2 * 4096;                              // bsum, base
    const size_t sz_wt2 = (size_t)256 * K * 2;
    const size_t sz_s   = (size_t)N * K * 2;
    int KZ = 1;
    for (int kz = 4; kz >= 1; kz >>= 1) {
        size_t r0 = (kz > 1) ? (size_t)kz * sz_pslice : 0;
        if (sz_sort > r0) r0 = sz_sort;
        size_t need = ((r0 + 255) & ~255UL) + ((sz_wt2 + 255) & ~255UL) + sz_s + 1024;
        if (need <= ws_size || kz == 1) { KZ = kz; break; }
    }

    char* ws = (char*)d_ws;
    size_t off = 0;
    auto alloc = [&](size_t bytes) { void* p = ws + off; off = (off + bytes + 255) & ~(size_t)255; return p; };
    float* pbuf = (float*)ws;  // aliases sort bufs (sort dead before gemm)
    int* deg    = (int*)alloc((size_t)B * 4);
    int* local  = (int*)alloc((size_t)B * 4);
    int* bsum   = (int*)alloc(4096);
    int* base   = (int*)alloc(4096);
    int* ctr    = (int*)alloc((size_t)B * 4);
    int* srcs   = (int*)alloc((size_t)E * 4);
    size_t region0 = (KZ > 1) ? (size_t)KZ * sz_pslice : 0;
    if (off > region0) region0 = off;
    off = (region0 + 255) & ~(size_t)255;
    unsigned short* Wt2 = (unsigned short*)alloc(sz_wt2);
    unsigned short* s   = (unsigned short*)alloc(sz_s);

    hipMemsetAsync(deg, 0, (size_t)B * 4, stream);
    {
        const int nh = (E + 255) / 256;
        const int nw = (R + 1) * 256;
        const int nx = (N * 64 + 255) / 256;
        prep_kernel<<<nh + nw + nx, 256, 0, stream>>>(dst, et, deg, Wr, W0w, Wt2, x, s,
                                                      E, N, R, nh, nw);
    }
    scan1_kernel<<<NC, 256, 0, stream>>>(deg, local, bsum, ctr, B);
    scan2_kernel<<<1, 1024, 0, stream>>>(bsum, base, NC);
    scatter_ids_kernel<<<(E + 255) / 256, 256, 0, stream>>>(src, dst, et, local, base, ctr, srcs, E, N);
    {
        dim3 g((N + 7) / 8, R);
        reduce_kernel<<<g, 256, 0, stream>>>(srcs, deg, local, base, s, N, R);
    }
    {
        const int ktot = K / 64;                  // 68
        const int ksteps = ktot / KZ;
        dim3 grid((N + 127) / 128, 2, KZ);
        if (KZ == 1) {
            gemm_kernel<<<grid, 256, 0, stream>>>(s, Wt2, W0b, out, N, K, ksteps, 1);
        } else {
            gemm_kernel<<<grid, 256, 0, stream>>>(s, Wt2, W0b, pbuf, N, K, ksteps, 0);
            combine_kernel<<<(N * 64 + 255) / 256, 256, 0, stream>>>(pbuf, W0b, out, N, KZ);
        }
    }
}